// Round 6
// baseline (442.270 us; speedup 1.0000x reference)
//
#include <hip/hip_runtime.h>
#include <hip/hip_fp16.h>
#include <cstdint>
#include <cstddef>

#define M_DIM 8192
#define N_DIM 4096
#define K_DIM 4096

typedef int v4i __attribute__((ext_vector_type(4)));

// ---------------------------------------------------------------------------
// Fused pack kernel: int32 (harness-widened int8) -> int8 for BOTH x and w in
// one launch. 16B coalesced load -> 4B coalesced store.
// ---------------------------------------------------------------------------
__global__ __launch_bounds__(256) void pack_i32_to_i8(const int* __restrict__ srcX,
                                                      uint32_t* __restrict__ dstX,
                                                      const int* __restrict__ srcW,
                                                      uint32_t* __restrict__ dstW,
                                                      int nx4, int ntot) {
    int i = blockIdx.x * 256 + threadIdx.x;
    if (i >= ntot) return;
    const int* s;
    uint32_t*  d;
    int j;
    if (i < nx4) { s = srcX; d = dstX; j = i; }
    else         { s = srcW; d = dstW; j = i - nx4; }
    int4 a = ((const int4*)s)[j];
#if __has_builtin(__builtin_amdgcn_perm)
    uint32_t lo = __builtin_amdgcn_perm((uint32_t)a.y, (uint32_t)a.x, 0x0400);
    uint32_t hi = __builtin_amdgcn_perm((uint32_t)a.w, (uint32_t)a.z, 0x0400);
    d[j] = __builtin_amdgcn_perm(hi, lo, 0x05040100);
#else
    d[j] = (uint32_t)(a.x & 0xff) | ((uint32_t)(a.y & 0xff) << 8) |
           ((uint32_t)(a.z & 0xff) << 16) | ((uint32_t)a.w << 24);
#endif
}

__device__ __forceinline__ void gload_lds16(const int8_t* g, int8_t* l) {
    __builtin_amdgcn_global_load_lds(
        (const __attribute__((address_space(1))) void*)g,
        (__attribute__((address_space(3))) void*)l, 16, 0, 0);
}

// ---------------------------------------------------------------------------
// GEMM: C[m][n] = sum_k A[m][k]*W[n][k], int32 acc, fused dequant epilogue.
//
// 256x256 tile, BK=64, 8 waves (2Mx4N), per-wave 128x64 via acc[8][4] of
// mfma_i32_16x16x64_i8.
//
// ROUND 10: FLAT-B (A via LDS, B direct global->VGPR). Rounds 5-9 showed the
// period is pinned at ~the SERIAL SUM of LDS work + MFMA regardless of
// schedule (r8: 2513 cy/tile; r9 manual waits: 2747 vs overlapped model
// 1540) -> on this structure LDS and MFMA barely overlap; the lever is to
// SHRINK THE LDS TERM. B's fragment layout (lane = n&15, k-chunk = lane>>4)
// is 16B-contiguous in the row-major W panel, so B fragments load directly
// from global (L2-resident: W panel reused by 32 M-blocks) into VGPRs:
//   qB[i] = W[bn*256 + wn*64 + i*16 + (lane&15)][kt*64 + (lane>>4)*16]
// LDS now carries A only: per-tile traffic 96+32=128 KB -> 64+16=80 KB.
// B double-buffered in regs, prefetch distance 1 tile (~850ns > L2 latency);
// compiler owns the vmcnt waits for B (r4-style codegen measured best).
//
// A staging: 4 LDS buffers x 16KB (64 KB), 3 tiles ahead, 2 gload_lds/thread
// per tile. A-frag register pipeline (P/Q, static swap): iter kt reads tile
// kt+1's A-frags, MFMAs tile kt.
//
// vmcnt ledger (per wave per iter: 4 B-loads (kt+1) then 2 A-stages (kt+3)):
//   prologue: A0,A1,A2 (6), B0 (4); VMW(6) -> A0,A1 landed; barrier.
//   iter kt<=60: issue B(kt+1),A(kt+3); MFMA(kt) (compiler's own vmcnt wait
//     for B(kt) drains through A(kt+2) since A(kt+2) is older); manual gate
//     VMW(6) (= B(kt+1)+A(kt+3) in flight) -> A(kt+2) landed; barrier ->
//     CU-wide visible for next iter's A-frag reads.
//   iter 61: no stage; VMW(4) -> A(63) landed. iters 62,63: no gate/barrier
//     (no LDS writes remain; B(63) guarded by compiler waits).
//   WAR: buf (kt+3)&3 holds tile kt-1, whose A-frags were read in iter kt-2;
//   two barriers separate. Safe.
//
// CHUNK-ROTATION SWIZZLE unchanged for A (0 bank conflicts).
// ---------------------------------------------------------------------------

#define VMW(n) asm volatile("s_waitcnt vmcnt(" #n ")" ::: "memory")

// 8 A-fragment ds_reads for tile KT1 (plain C++ -> compiler lgkm waits).
#define LOADFA(DA, DC, KT1)                                                   \
    do {                                                                      \
        const int8_t* _b = lds + ((KT1) & 3) * 16384;                         \
        _Pragma("unroll")                                                     \
        for (int i = 0; i < 4; ++i) {                                         \
            DA[i] = *(const v4i*)(_b + aoff + i * 1024);                      \
            DC[i] = *(const v4i*)(_b + aoff + 4096 + i * 1024);               \
        }                                                                     \
    } while (0)

// 4 B-fragment direct global loads for tile KT1 (plain C++ -> compiler vmcnt).
#define LOADB(DB, KT1)                                                        \
    do {                                                                      \
        _Pragma("unroll")                                                     \
        for (int i = 0; i < 4; ++i)                                           \
            DB[i] = *(const v4i*)(gBL + (size_t)i * (16 * K_DIM) + (KT1) * 64); \
    } while (0)

#define STAGEA(KT3)                                                           \
    do {                                                                      \
        int8_t* _s = lds + ((KT3) & 3) * 16384;                               \
        gload_lds16(gA0 + (KT3) * 64, _s + ldsoff);                           \
        gload_lds16(gA1 + (KT3) * 64, _s + ldsoff + 8192);                    \
    } while (0)

#define MFMA32(CA, CB, CC)                                                    \
    __builtin_amdgcn_s_setprio(1);                                            \
    _Pragma("unroll")                                                         \
    for (int mi = 0; mi < 4; ++mi) {                                          \
        _Pragma("unroll")                                                     \
        for (int ni = 0; ni < 4; ++ni)                                        \
            acc[mi][ni] = __builtin_amdgcn_mfma_i32_16x16x64_i8(              \
                CA[mi], CB[ni], acc[mi][ni], 0, 0, 0);                        \
    }                                                                         \
    _Pragma("unroll")                                                         \
    for (int mi = 0; mi < 4; ++mi) {                                          \
        _Pragma("unroll")                                                     \
        for (int ni = 0; ni < 4; ++ni)                                        \
            acc[4 + mi][ni] = __builtin_amdgcn_mfma_i32_16x16x64_i8(          \
                CC[mi], CB[ni], acc[4 + mi][ni], 0, 0, 0);                    \
    }                                                                         \
    __builtin_amdgcn_s_setprio(0);

// One K-tile iteration. CUR frags (CA,CB,CC) hold tile KT (read/loaded last
// iter); NXT frags receive tile KT+1. All flags compile-time.
#define ITER(KT, CA, CB, CC, NA, NB, NC, DOREAD, DOSTAGE, VMSTMT, DOSYNC)     \
    do {                                                                      \
        if (DOREAD) {                                                         \
            LOADB(NB, (KT) + 1);                                              \
            LOADFA(NA, NC, (KT) + 1);                                         \
        }                                                                     \
        if (DOSTAGE) STAGEA((KT) + 3);                                        \
        __builtin_amdgcn_sched_barrier(0);                                    \
        MFMA32(CA, CB, CC);                                                   \
        if (DOSYNC) {                                                         \
            __builtin_amdgcn_sched_barrier(0);                                \
            VMSTMT;                                                           \
            __builtin_amdgcn_s_barrier();                                     \
            __builtin_amdgcn_sched_barrier(0);                                \
        }                                                                     \
    } while (0)

__global__ __launch_bounds__(512, 2) void gemm_i8_dq(const int8_t* __restrict__ A,
                                                     const int8_t* __restrict__ W,
                                                     const float* __restrict__ sx,
                                                     const float* __restrict__ sw,
                                                     const float* __restrict__ bias,
                                                     float* __restrict__ out) {
    __shared__ __attribute__((aligned(16))) int8_t lds[65536];  // 4 bufs x 16KB (A only)

    const int t    = threadIdx.x;
    const int lane = t & 63;
    const int w    = t >> 6;          // 0..7
    const int wm   = w >> 2;          // 0..1  (M halves of the 256-row tile)
    const int wn   = w & 3;           // 0..3  (N quarters)

    // XCD swizzle: 512 blocks, 8 XCDs, each XCD owns an 8(M) x 8(N) patch.
    const int flat = blockIdx.y * 16 + blockIdx.x;   // 0..511
    const int xcd  = flat & 7;
    const int idx  = flat >> 3;                      // 0..63
    const int bm   = (xcd >> 1) * 8 + (idx & 7);     // 0..31
    const int bn   = (xcd & 1) * 8 + (idx >> 3);     // 0..15

    // ---- A staging addresses (2 gload_lds/thread per K-tile) ----
    const int srow   = t >> 2;                       // 0..127
    const int rot    = (srow >> 1) & 3;
    const int gchunk = ((t & 3) + rot) & 3;          // rotated 16B chunk
    const int scol   = gchunk * 16;
    const int8_t* gA0 = A + (size_t)(bm * 256 + srow) * K_DIM + scol;
    const int8_t* gA1 = gA0 + (size_t)128 * K_DIM;
    const int ldsoff = t * 16;                       // linear dst within region

    // ---- A fragment read addresses (chunk-rotation inverse) ----
    const int rho  = lane & 15;
    const int p16  = (((lane >> 4) - (rho >> 1)) & 3) * 16;
    const int aoff = (wm * 128 + rho) * 64 + p16;

    // ---- B direct-load base: lane holds W[n-group + lane&15][chunk lane>>4]
    const int8_t* gBL = W + (size_t)(bn * 256 + wn * 64 + (lane & 15)) * K_DIM
                          + ((lane >> 4) * 16);

    v4i acc[8][4];
    const v4i vzero = {0, 0, 0, 0};
#pragma unroll
    for (int mi = 0; mi < 8; mi++)
#pragma unroll
        for (int ni = 0; ni < 4; ni++) acc[mi][ni] = vzero;

    // Double-buffered fragment sets (statically swapped; no dynamic index).
    v4i pA[4], pB[4], pC[4], qA[4], qB[4], qC[4];

    // ---- prologue: stage A 0..2, load B0, land A0+A1, read A0 frags ----
#pragma unroll
    for (int pt = 0; pt < 3; ++pt) {
        int8_t* bufA = lds + pt * 16384;
        gload_lds16(gA0 + pt * 64, bufA + ldsoff);
        gload_lds16(gA1 + pt * 64, bufA + ldsoff + 8192);
    }
    LOADB(pB, 0);
    __builtin_amdgcn_sched_barrier(0);
    VMW(6);                           // A0,A1 landed (A2 + B0 in flight)
    __builtin_amdgcn_s_barrier();
    __builtin_amdgcn_sched_barrier(0);
    LOADFA(pA, pC, 0);                // tile-0 A-fragments -> P

    // ---- main loop: 64 K-tiles, unrolled x2 (P/Q swap) ----
    for (int kt = 0; kt < 60; kt += 2) {
        ITER(kt,     pA, pB, pC, qA, qB, qC, true, true, VMW(6), true);
        ITER(kt + 1, qA, qB, qC, pA, pB, pC, true, true, VMW(6), true);
    }
    ITER(60, pA, pB, pC, qA, qB, qC, true,  true,  VMW(6),    true);
    ITER(61, qA, qB, qC, pA, pB, pC, true,  false, VMW(4),    true);
    ITER(62, pA, pB, pC, qA, qB, qC, true,  false, ((void)0), false);
    ITER(63, qA, qB, qC, pA, pB, pC, false, false, ((void)0), false);

    // ---- epilogue: C/D 16x16 layout: col = lane&15, row = (lane>>4)*4 + r --
    const float DIVF = (float)(1.0 / (127.0 * 127.0));
    const int col0 = bn * 256 + wn * 64 + (lane & 15);
    const int row0 = bm * 256 + wm * 128 + (lane >> 4) * 4;

    float swv[4], bv[4];
#pragma unroll
    for (int ni = 0; ni < 4; ni++) {
        swv[ni] = sw[col0 + ni * 16];
        bv[ni]  = bias[col0 + ni * 16];
    }

#pragma unroll
    for (int mi = 0; mi < 8; mi++) {
#pragma unroll
        for (int r = 0; r < 4; r++) {
            const int row = row0 + mi * 16 + r;
            const float xs = sx[row];
#pragma unroll
            for (int ni = 0; ni < 4; ni++) {
                // numpy op order: ((acc_f * DIV) * sx) * sw + bias, no fma
                float v = __fmul_rn((float)acc[mi][ni][r], DIVF);
                v = __fmul_rn(v, xs);
                v = __fmul_rn(v, swv[ni]);
                v = __fadd_rn(v, bv[ni]);
                out[(size_t)row * N_DIM + col0 + ni * 16] = __half2float(__float2half(v));
            }
        }
    }
}

extern "C" void kernel_launch(void* const* d_in, const int* in_sizes, int n_in,
                              void* d_out, int out_size, void* d_ws, size_t ws_size,
                              hipStream_t stream) {
    const int*   x_i32 = (const int*)d_in[0];      // [M,K] int (widened int8)
    const float* sx    = (const float*)d_in[1];    // [M] f32
    const int*   w_i32 = (const int*)d_in[2];      // [N,K] int (widened int8)
    const float* sw    = (const float*)d_in[3];    // [N] f32
    const float* bias  = (const float*)d_in[4];    // [N] f32 (widened fp16)
    float* out = (float*)d_out;                    // [M,N] f32 (widened fp16)

    uint8_t* xb = (uint8_t*)d_ws;                          // 32 MB packed x
    uint8_t* wb = (uint8_t*)d_ws + (size_t)M_DIM * K_DIM;  // 16 MB packed w

    const int nx4  = (M_DIM * K_DIM) / 4;
    const int nw4  = (N_DIM * K_DIM) / 4;
    const int ntot = nx4 + nw4;
    pack_i32_to_i8<<<(ntot + 255) / 256, 256, 0, stream>>>(
        x_i32, (uint32_t*)xb, w_i32, (uint32_t*)wb, nx4, ntot);

    dim3 grid(N_DIM / 256, M_DIM / 256);  // (16, 32) = 512 blocks
    gemm_i8_dq<<<grid, 512, 0, stream>>>((const int8_t*)xb, (const int8_t*)wb,
                                         sx, sw, bias, out);
}

// Round 8
// 385.063 us; speedup vs baseline: 1.1486x; 1.1486x over previous
//
#include <hip/hip_runtime.h>
#include <hip/hip_fp16.h>
#include <cstdint>
#include <cstddef>

#define M_DIM 8192
#define N_DIM 4096
#define K_DIM 4096

typedef int v4i __attribute__((ext_vector_type(4)));

// ---------------------------------------------------------------------------
// Fused pack kernel (v1, known-good): int32 (harness-widened int8) -> int8
// for BOTH x and w in one launch. 16B coalesced load -> 4B coalesced store.
// Pack is HBM-bound (192MB read + 48MB write ~= 38us floor) — v1 is at it.
// [r7's v2 (16B stores) had a 4x store-index bug -> absmax 2.4. Reverted.]
// ---------------------------------------------------------------------------
__global__ __launch_bounds__(256) void pack_i32_to_i8(const int* __restrict__ srcX,
                                                      uint32_t* __restrict__ dstX,
                                                      const int* __restrict__ srcW,
                                                      uint32_t* __restrict__ dstW,
                                                      int nx4, int ntot) {
    int i = blockIdx.x * 256 + threadIdx.x;
    if (i >= ntot) return;
    const int* s;
    uint32_t*  d;
    int j;
    if (i < nx4) { s = srcX; d = dstX; j = i; }
    else         { s = srcW; d = dstW; j = i - nx4; }
    int4 a = ((const int4*)s)[j];
#if __has_builtin(__builtin_amdgcn_perm)
    uint32_t lo = __builtin_amdgcn_perm((uint32_t)a.y, (uint32_t)a.x, 0x0400);
    uint32_t hi = __builtin_amdgcn_perm((uint32_t)a.w, (uint32_t)a.z, 0x0400);
    d[j] = __builtin_amdgcn_perm(hi, lo, 0x05040100);
#else
    d[j] = (uint32_t)(a.x & 0xff) | ((uint32_t)(a.y & 0xff) << 8) |
           ((uint32_t)(a.z & 0xff) << 16) | ((uint32_t)a.w << 24);
#endif
}

__device__ __forceinline__ void gload_lds16(const int8_t* g, int8_t* l) {
    __builtin_amdgcn_global_load_lds(
        (const __attribute__((address_space(1))) void*)g,
        (__attribute__((address_space(3))) void*)l, 16, 0, 0);
}

// ---------------------------------------------------------------------------
// GEMM: C[m][n] = sum_k A[m][k]*W[n][k], int32 acc, fused dequant epilogue.
//
// 256x256 tile, BK=64, 8 waves (2Mx4N), per-wave 128x64 via acc[8][4] of
// mfma_i32_16x16x64_i8. 4 LDS K-tile buffers (128 KB), staging 3 tiles ahead
// via global_load_lds, counted vmcnt. Register pipeline: iter kt reads tile
// kt+1's fragments (P/Q static swap), MFMAs tile kt.
//
// ROUND 11/12: FINE-GRAINED DS/MFMA INTERLEAVE. r4-r9 all pinned at the
// serial sum of DS-pipe occupancy (~1540 cy/tile: 96 ds_read_b128 @ ~12cy +
// stage writes) + MFMA (~1306 cy) because the 12 frag reads issued as ONE
// BURST: 8 waves dump 96 reads into the DS queue at the top of each iter,
// waves stall mid-issue on the queue, MFMA starts after the drain, DS idles
// during the MFMA burst. Fix: split each iter into 4 sub-batches
//   { 3 frag-reads(kt+1) | 1 gload_lds(kt+3) } ; sched_barrier ;
//   setprio(1) ; 8 MFMA(kt) ; setprio(0) ; sched_barrier
// Per batch ~36cy DS work under ~41cy MFMA -> both pipes continuously fed.
// No semantic change: MFMA operands are last iter's regs, independent of the
// reads in flight; compiler still inserts counted lgkm waits before the first
// consuming MFMA of the NEXT iter (r4-style codegen, measured best).
//
// vmcnt ledger (4 loads/tile; tile kt+1 is READ in iter kt => resident at
// END of iter kt-1):
//   prologue: stage 0,1,2; vmcnt(4) -> tiles 0 AND 1 landed; barrier.
//   iter kt<=60: stage kt+3 (spread over batches, same issue order as r4);
//     gate vmcnt(4) -> tile kt+2 landed; barrier -> CU-wide visible.
//   iter 61: no stage; gate vmcnt(0). iters 62,63: no gate/barrier.
//   WAR: buf (kt+1)&3 rewritten by stage of kt+5 (iter kt+2), one barrier
//   after all waves' reads completed. Safe. (Ledger identical to r4/passed.)
//
// CHUNK-ROTATION SWIZZLE unchanged (0 bank conflicts): LDS slot [row*64+p*16]
// holds global k-chunk (p + (row>>1)) & 3; fragment read inverts it.
// ---------------------------------------------------------------------------

#define VMW(n) asm volatile("s_waitcnt vmcnt(" #n ")" ::: "memory")
#define SB()   __builtin_amdgcn_sched_barrier(0)

// 8 MFMAs: two m-fragments X0,X1 against all 4 B-fragments of CB.
#define MFMA8(X0, X1, R0, R1, CB)                                             \
    __builtin_amdgcn_s_setprio(1);                                            \
    _Pragma("unroll")                                                         \
    for (int ni = 0; ni < 4; ++ni)                                            \
        acc[R0][ni] = __builtin_amdgcn_mfma_i32_16x16x64_i8(                  \
            X0, CB[ni], acc[R0][ni], 0, 0, 0);                                \
    _Pragma("unroll")                                                         \
    for (int ni = 0; ni < 4; ++ni)                                            \
        acc[R1][ni] = __builtin_amdgcn_mfma_i32_16x16x64_i8(                  \
            X1, CB[ni], acc[R1][ni], 0, 0, 0);                                \
    __builtin_amdgcn_s_setprio(0);

// One K-tile iteration, 4 interleaved sub-batches.
// CUR frags (CA,CB,CC) hold tile KT (read last iter); NXT receive tile KT+1.
#define ITER(KT, CA, CB, CC, NA, NB, NC, DOREAD, DOSTAGE, VMSTMT, DOSYNC)     \
    do {                                                                      \
        const int8_t* _b = lds + (((KT) + 1) & 3) * 32768;                    \
        int8_t*       _s = lds + (((KT) + 3) & 3) * 32768;                    \
        /* batch 0 */                                                         \
        if (DOREAD) {                                                         \
            NA[0] = *(const v4i*)(_b + aoff);                                 \
            NB[0] = *(const v4i*)(_b + 16384 + boff);                         \
            NC[0] = *(const v4i*)(_b + aoff + 4096);                          \
        }                                                                     \
        if (DOSTAGE) gload_lds16(gA0 + ((KT) + 3) * 64, _s + ldsoff);         \
        SB();                                                                 \
        MFMA8(CA[0], CA[1], 0, 1, CB);                                        \
        SB();                                                                 \
        /* batch 1 */                                                         \
        if (DOREAD) {                                                         \
            NA[1] = *(const v4i*)(_b + aoff + 1024);                          \
            NB[1] = *(const v4i*)(_b + 16384 + boff + 1024);                  \
            NC[1] = *(const v4i*)(_b + aoff + 5120);                          \
        }                                                                     \
        if (DOSTAGE) gload_lds16(gA1 + ((KT) + 3) * 64, _s + ldsoff + 8192);  \
        SB();                                                                 \
        MFMA8(CA[2], CA[3], 2, 3, CB);                                        \
        SB();                                                                 \
        /* batch 2 */                                                         \
        if (DOREAD) {                                                         \
            NA[2] = *(const v4i*)(_b + aoff + 2048);                          \
            NB[2] = *(const v4i*)(_b + 16384 + boff + 2048);                  \
            NC[2] = *(const v4i*)(_b + aoff + 6144);                          \
        }                                                                     \
        if (DOSTAGE) gload_lds16(gB0 + ((KT) + 3) * 64, _s + 16384 + ldsoff); \
        SB();                                                                 \
        MFMA8(CC[0], CC[1], 4, 5, CB);                                        \
        SB();                                                                 \
        /* batch 3 */                                                         \
        if (DOREAD) {                                                         \
            NA[3] = *(const v4i*)(_b + aoff + 3072);                          \
            NB[3] = *(const v4i*)(_b + 16384 + boff + 3072);                  \
            NC[3] = *(const v4i*)(_b + aoff + 7168);                          \
        }                                                                     \
        if (DOSTAGE) gload_lds16(gB1 + ((KT) + 3) * 64,                       \
                                 _s + 16384 + ldsoff + 8192);                 \
        SB();                                                                 \
        MFMA8(CC[2], CC[3], 6, 7, CB);                                        \
        SB();                                                                 \
        if (DOSYNC) {                                                         \
            VMSTMT;                                                           \
            __builtin_amdgcn_s_barrier();                                     \
            SB();                                                             \
        }                                                                     \
    } while (0)

// Bulk 12-read fragment load (prologue only).
#define LOADF(DA, DB, DC, KT1)                                                \
    do {                                                                      \
        const int8_t* _b = lds + (((KT1) & 3) * 32768);                       \
        _Pragma("unroll")                                                     \
        for (int i = 0; i < 4; ++i) {                                         \
            DA[i] = *(const v4i*)(_b + aoff + i * 1024);                      \
            DB[i] = *(const v4i*)(_b + 16384 + boff + i * 1024);              \
            DC[i] = *(const v4i*)(_b + aoff + 4096 + i * 1024);               \
        }                                                                     \
    } while (0)

__global__ __launch_bounds__(512, 2) void gemm_i8_dq(const int8_t* __restrict__ A,
                                                     const int8_t* __restrict__ W,
                                                     const float* __restrict__ sx,
                                                     const float* __restrict__ sw,
                                                     const float* __restrict__ bias,
                                                     float* __restrict__ out) {
    __shared__ __attribute__((aligned(16))) int8_t lds[131072];  // 4 bufs x (16KB A + 16KB B)

    const int t    = threadIdx.x;
    const int lane = t & 63;
    const int w    = t >> 6;          // 0..7
    const int wm   = w >> 2;          // 0..1  (M halves of the 256-row tile)
    const int wn   = w & 3;           // 0..3  (N quarters)

    // XCD swizzle: 512 blocks, 8 XCDs, each XCD owns an 8(M) x 8(N) patch.
    const int flat = blockIdx.y * 16 + blockIdx.x;   // 0..511
    const int xcd  = flat & 7;
    const int idx  = flat >> 3;                      // 0..63
    const int bm   = (xcd >> 1) * 8 + (idx & 7);     // 0..31
    const int bn   = (xcd & 1) * 8 + (idx >> 3);     // 0..15

    // ---- staging addresses (4 gload_lds/thread per K-tile: 2 A + 2 B) ----
    const int srow   = t >> 2;                       // 0..127
    const int rot    = (srow >> 1) & 3;
    const int gchunk = ((t & 3) + rot) & 3;          // rotated 16B chunk
    const int scol   = gchunk * 16;
    const int8_t* gA0 = A + (size_t)(bm * 256 + srow) * K_DIM + scol;
    const int8_t* gA1 = gA0 + (size_t)128 * K_DIM;
    const int8_t* gB0 = W + (size_t)(bn * 256 + srow) * K_DIM + scol;
    const int8_t* gB1 = gB0 + (size_t)128 * K_DIM;
    const int ldsoff = t * 16;                       // linear dst within region

    // ---- fragment read addresses (chunk-rotation inverse) ----
    const int rho  = lane & 15;
    const int p16  = (((lane >> 4) - (rho >> 1)) & 3) * 16;
    const int aoff = (wm * 128 + rho) * 64 + p16;
    const int boff = (wn * 64 + rho) * 64 + p16;

    v4i acc[8][4];
    const v4i vzero = {0, 0, 0, 0};
#pragma unroll
    for (int mi = 0; mi < 8; mi++)
#pragma unroll
        for (int ni = 0; ni < 4; ni++) acc[mi][ni] = vzero;

    // Double-buffered fragment sets (statically swapped; no dynamic index).
    v4i pA[4], pB[4], pC[4], qA[4], qB[4], qC[4];

    // ---- prologue: stage K-tiles 0..2, land tiles 0 AND 1, read tile 0 ----
#pragma unroll
    for (int pt = 0; pt < 3; ++pt) {
        int8_t* bufA = lds + pt * 32768;
        gload_lds16(gA0 + pt * 64, bufA + ldsoff);
        gload_lds16(gA1 + pt * 64, bufA + ldsoff + 8192);
        gload_lds16(gB0 + pt * 64, bufA + 16384 + ldsoff);
        gload_lds16(gB1 + pt * 64, bufA + 16384 + ldsoff + 8192);
    }
    VMW(4);                           // tiles 0,1 landed (tile 2 in flight)
    __builtin_amdgcn_s_barrier();
    SB();
    LOADF(pA, pB, pC, 0);             // tile-0 fragments -> P

    // ---- main loop: 64 K-tiles, unrolled x2 (P/Q swap) ----
    for (int kt = 0; kt < 60; kt += 2) {
        ITER(kt,     pA, pB, pC, qA, qB, qC, true, true, VMW(4), true);
        ITER(kt + 1, qA, qB, qC, pA, pB, pC, true, true, VMW(4), true);
    }
    ITER(60, pA, pB, pC, qA, qB, qC, true,  true,  VMW(4),    true);
    ITER(61, qA, qB, qC, pA, pB, pC, true,  false, VMW(0),    true);
    ITER(62, pA, pB, pC, qA, qB, qC, true,  false, ((void)0), false);
    ITER(63, qA, qB, qC, pA, pB, pC, false, false, ((void)0), false);

    // ---- epilogue: C/D 16x16 layout: col = lane&15, row = (lane>>4)*4 + r --
    const float DIVF = (float)(1.0 / (127.0 * 127.0));
    const int col0 = bn * 256 + wn * 64 + (lane & 15);
    const int row0 = bm * 256 + wm * 128 + (lane >> 4) * 4;

    float swv[4], bv[4];
#pragma unroll
    for (int ni = 0; ni < 4; ni++) {
        swv[ni] = sw[col0 + ni * 16];
        bv[ni]  = bias[col0 + ni * 16];
    }

#pragma unroll
    for (int mi = 0; mi < 8; mi++) {
#pragma unroll
        for (int r = 0; r < 4; r++) {
            const int row = row0 + mi * 16 + r;
            const float xs = sx[row];
#pragma unroll
            for (int ni = 0; ni < 4; ni++) {
                // numpy op order: ((acc_f * DIV) * sx) * sw + bias, no fma
                float v = __fmul_rn((float)acc[mi][ni][r], DIVF);
                v = __fmul_rn(v, xs);
                v = __fmul_rn(v, swv[ni]);
                v = __fadd_rn(v, bv[ni]);
                out[(size_t)row * N_DIM + col0 + ni * 16] = __half2float(__float2half(v));
            }
        }
    }
}

extern "C" void kernel_launch(void* const* d_in, const int* in_sizes, int n_in,
                              void* d_out, int out_size, void* d_ws, size_t ws_size,
                              hipStream_t stream) {
    const int*   x_i32 = (const int*)d_in[0];      // [M,K] int (widened int8)
    const float* sx    = (const float*)d_in[1];    // [M] f32
    const int*   w_i32 = (const int*)d_in[2];      // [N,K] int (widened int8)
    const float* sw    = (const float*)d_in[3];    // [N] f32
    const float* bias  = (const float*)d_in[4];    // [N] f32 (widened fp16)
    float* out = (float*)d_out;                    // [M,N] f32 (widened fp16)

    uint8_t* xb = (uint8_t*)d_ws;                          // 32 MB packed x
    uint8_t* wb = (uint8_t*)d_ws + (size_t)M_DIM * K_DIM;  // 16 MB packed w

    const int nx4  = (M_DIM * K_DIM) / 4;
    const int nw4  = (N_DIM * K_DIM) / 4;
    const int ntot = nx4 + nw4;
    pack_i32_to_i8<<<(ntot + 255) / 256, 256, 0, stream>>>(
        x_i32, (uint32_t*)xb, w_i32, (uint32_t*)wb, nx4, ntot);

    dim3 grid(N_DIM / 256, M_DIM / 256);  // (16, 32) = 512 blocks
    gemm_i8_dq<<<grid, 512, 0, stream>>>((const int8_t*)xb, (const int8_t*)wb,
                                         sx, sw, bias, out);
}